// Round 15
// baseline (470.026 us; speedup 1.0000x reference)
//
#include <hip/hip_runtime.h>
#include <math.h>
#include <stdint.h>

#define N_NODES 16384
#define N_EDGES 262144
#define HID 128
#define NRBF 20
#define CUTOFF 5.0f
#define PI_F 3.14159265358979323846f

#define CSTRIDE 16

typedef __attribute__((ext_vector_type(2))) __fp16 half2_t;
union U32H2 { uint32_t u; half2_t h; float f; };

__device__ inline unsigned short f2bf(float f) {
    unsigned int u = __float_as_uint(f);
    u = u + 0x7FFFu + ((u >> 16) & 1u);
    return (unsigned short)(u >> 16);
}
__device__ inline uint32_t pack2(float lo, float hi) {
    return (uint32_t)f2bf(lo) | ((uint32_t)f2bf(hi) << 16);
}
__device__ inline float blo(uint32_t u) { return __uint_as_float(u << 16); }
__device__ inline float bhi(uint32_t u) { return __uint_as_float(u & 0xFFFF0000u); }
__device__ inline uint32_t pkh2(float a, float b) {
    U32H2 u; u.h = __builtin_amdgcn_cvt_pkrtz(a, b); return u.u;
}

// ---------------------------------------------------------------------------
// Kernel 0: prep — zero cnt AND pre-pack W1/W2/Wrbf as f16 pairs (once).
// ---------------------------------------------------------------------------
__global__ __launch_bounds__(256) void prep_kernel(
    const float* __restrict__ W1, const float* __restrict__ W2,
    const float* __restrict__ Wrbf,
    int* __restrict__ cnt, uint32_t* __restrict__ W1p,
    uint32_t* __restrict__ W2p, uint32_t* __restrict__ Wrbfp)
{
    const int id = blockIdx.x * 256 + threadIdx.x;
    if (id < 16384) {
        cnt[id] = 0;
    } else if (id < 24576) {
        const int i = id - 16384;
        const int kp = i >> 7, t = i & 127;
        W1p[i] = pkh2(W1[(size_t)(2 * kp) * HID + t],
                      W1[(size_t)(2 * kp + 1) * HID + t]);
    } else if (id < 49152) {
        const int i = id - 24576;
        const int kp = i / 384, rem = i % 384;
        W2p[i] = pkh2(W2[(size_t)(2 * kp) * 384 + rem],
                      W2[(size_t)(2 * kp + 1) * 384 + rem]);
    } else if (id < 49152 + 3840) {
        const int i = id - 49152;
        const int j = i / 384, rem = i % 384;
        Wrbfp[i] = pkh2(Wrbf[(size_t)(2 * j) * 384 + rem],
                        Wrbf[(size_t)(2 * j + 1) * 384 + rem]);
    }
}

// ---------------------------------------------------------------------------
// Kernel 1: phi = silu(s@W1+b1)@W2+b2 via fdot2 on pre-packed weights.
// 512 threads/block, 32 nodes/block. Fused histogram. Writes 12 B/channel
// records g12[node*128+ch] = {(phi0,phi1),(phi2,v0),(v1,v2)} bf16 pairs.
// ---------------------------------------------------------------------------
#define PB 32
__global__ __launch_bounds__(512, 4) void phi_kernel(
    const float* __restrict__ s, const float* __restrict__ v,
    const uint32_t* __restrict__ W1p, const float* __restrict__ b1,
    const uint32_t* __restrict__ W2p, const float* __restrict__ b2,
    const int* __restrict__ edst, int* __restrict__ cnt,
    uint3* __restrict__ g12)
{
    const int tid = threadIdx.x;
    const int ch  = tid & 127;
    const int sub = tid >> 7;            // 0..3 -> nodes sub*8 .. sub*8+7
    const int node0 = blockIdx.x * PB;

    atomicAdd(&cnt[edst[blockIdx.x * 512 + tid]], 1);

    __shared__ uint32_t sL2[PB][64];     // 8 KB
    __shared__ float    hL[PB][HID];     // 16 KB
    __shared__ uint32_t hL2[PB][64];     // 8 KB

    #pragma unroll
    for (int q = 0; q < 4; ++q) {
        const int idx = q * 512 + tid;
        const int i = idx >> 6, c = idx & 63;
        const float2 sv = *(const float2*)&s[(size_t)(node0 + i) * HID + 2 * c];
        sL2[i][c] = pkh2(sv.x, sv.y);
    }
    __syncthreads();

    float h[8];
    const float bb1 = b1[ch];
    #pragma unroll
    for (int i = 0; i < 8; ++i) h[i] = bb1;

    for (int kp = 0; kp < 64; kp += 2) {
        U32H2 wa; wa.u = W1p[kp * 128 + ch];
        U32H2 wb; wb.u = W1p[(kp + 1) * 128 + ch];
        #pragma unroll
        for (int i = 0; i < 8; ++i) {
            U32H2 ca; ca.u = sL2[sub * 8 + i][kp];
            U32H2 cb; cb.u = sL2[sub * 8 + i][kp + 1];
            h[i] = __builtin_amdgcn_fdot2(ca.h, wa.h, h[i], false);
            h[i] = __builtin_amdgcn_fdot2(cb.h, wb.h, h[i], false);
        }
    }
    #pragma unroll
    for (int i = 0; i < 8; ++i) {
        const float x = h[i];
        hL[sub * 8 + i][ch] = x / (1.0f + expf(-x));
    }
    __syncthreads();
    #pragma unroll
    for (int q = 0; q < 4; ++q) {
        const int idx = q * 512 + tid;
        const int i = idx >> 6, c = idx & 63;
        hL2[i][c] = pkh2(hL[i][2 * c], hL[i][2 * c + 1]);
    }
    __syncthreads();

    float a0[8], a1[8], a2[8];
    #pragma unroll
    for (int i = 0; i < 8; ++i) { a0[i] = 0.f; a1[i] = 0.f; a2[i] = 0.f; }

    for (int kp = 0; kp < 64; ++kp) {
        U32H2 wA; wA.u = W2p[(kp * 3 + 0) * 128 + ch];
        U32H2 wB; wB.u = W2p[(kp * 3 + 1) * 128 + ch];
        U32H2 wC; wC.u = W2p[(kp * 3 + 2) * 128 + ch];
        #pragma unroll
        for (int i = 0; i < 8; ++i) {
            U32H2 hh; hh.u = hL2[sub * 8 + i][kp];
            a0[i] = __builtin_amdgcn_fdot2(hh.h, wA.h, a0[i], false);
            a1[i] = __builtin_amdgcn_fdot2(hh.h, wB.h, a1[i], false);
            a2[i] = __builtin_amdgcn_fdot2(hh.h, wC.h, a2[i], false);
        }
    }
    const float bb2a = b2[ch], bb2b = b2[128 + ch], bb2c = b2[256 + ch];
    #pragma unroll
    for (int i = 0; i < 8; ++i) {
        const int node = node0 + sub * 8 + i;
        const size_t nrow = (size_t)node * 384;
        const float p0 = a0[i] + bb2a;
        const float p1 = a1[i] + bb2b;
        const float p2 = a2[i] + bb2c;
        const float v0 = v[nrow + ch];
        const float v1 = v[nrow + 128 + ch];
        const float v2 = v[nrow + 256 + ch];
        g12[(size_t)node * HID + ch] =
            make_uint3(pack2(p0, p1), pack2(p2, v0), pack2(v1, v2));
    }
}

// ---------------------------------------------------------------------------
// CSR build: scan -> scatter
// ---------------------------------------------------------------------------
__global__ __launch_bounds__(256) void scan_kernel(const int* __restrict__ cnt,
                                                   int* __restrict__ row_ptr,
                                                   int* __restrict__ cur)
{
    __shared__ int part[256];
    const int tid = threadIdx.x;
    const int4* c4 = (const int4*)cnt;

    int4 loc[16];
    int s = 0;
    #pragma unroll
    for (int j = 0; j < 16; ++j) {
        loc[j] = c4[tid * 16 + j];
        s += loc[j].x + loc[j].y + loc[j].z + loc[j].w;
    }
    part[tid] = s;
    __syncthreads();
    #pragma unroll
    for (int d = 1; d < 256; d <<= 1) {
        const int add = (tid >= d) ? part[tid - d] : 0;
        __syncthreads();
        part[tid] += add;
        __syncthreads();
    }
    int off = (tid == 0) ? 0 : part[tid - 1];
    const int base = tid * 64;
    #pragma unroll
    for (int j = 0; j < 16; ++j) {
        const int4 q = loc[j];
        row_ptr[base + j*4 + 0] = off; cur[base + j*4 + 0] = off; off += q.x;
        row_ptr[base + j*4 + 1] = off; cur[base + j*4 + 1] = off; off += q.y;
        row_ptr[base + j*4 + 2] = off; cur[base + j*4 + 2] = off; off += q.z;
        row_ptr[base + j*4 + 3] = off; cur[base + j*4 + 3] = off; off += q.w;
    }
    if (tid == 255) row_ptr[16384] = off;
}

__global__ __launch_bounds__(256) void scatter_kernel(
    const float* __restrict__ r_ij, const int* __restrict__ esrc,
    const int* __restrict__ edst, int* __restrict__ cur,
    int* __restrict__ soff, uint32_t* __restrict__ coef)
{
    const int e = blockIdx.x * 256 + threadIdx.x;
    if (e >= N_EDGES) return;
    const float rx = r_ij[(size_t)e * 3 + 0];
    const float ry = r_ij[(size_t)e * 3 + 1];
    const float rz = r_ij[(size_t)e * 3 + 2];
    const float d = sqrtf(rx * rx + ry * ry + rz * rz);
    const float inv_d = 1.0f / d;
    float sx, cx;
    sincosf((PI_F / CUTOFF) * d, &sx, &cx);
    const float fcut = (d < CUTOFF) ? 0.5f * (cx + 1.0f) : 0.0f;

    float cf[NRBF];
    const float gfac = inv_d * fcut;
    const float twocx = 2.0f * cx;
    float sm1 = sx, sm2 = 0.0f;
    cf[0] = sx * gfac;
    #pragma unroll
    for (int n = 1; n < NRBF; ++n) {
        const float sn = twocx * sm1 - sm2;
        sm2 = sm1; sm1 = sn;
        cf[n] = sn * gfac;
    }

    uint32_t cp[10];
    #pragma unroll
    for (int j = 0; j < 10; ++j) cp[j] = pkh2(cf[2 * j], cf[2 * j + 1]);

    const int pos = atomicAdd(&cur[edst[e]], 1);
    soff[pos] = esrc[e] * 128;
    uint4* c4 = (uint4*)(coef + (size_t)pos * CSTRIDE);
    c4[0] = make_uint4(__float_as_uint(rx * inv_d), __float_as_uint(ry * inv_d),
                       __float_as_uint(rz * inv_d), __float_as_uint(fcut));
    c4[1] = make_uint4(cp[0], cp[1], cp[2], cp[3]);
    c4[2] = make_uint4(cp[4], cp[5], cp[6], cp[7]);
    c4[3] = make_uint4(cp[8], cp[9], 0u, 0u);
}

// ---------------------------------------------------------------------------
// Gather: node per 128-thread group; batch-4 edges; depth-2 ping-pong;
// ONE dwordx3 (12 B) gather per edge-thread; scalar coef/soff loads + K$
// warm; fdot2 on pre-packed weights pinned via asm. launch_bounds(256,8):
// VGPR cap 64 (current use 40 — no spill), occupancy ceiling 32 waves/CU.
// ---------------------------------------------------------------------------
__global__ __launch_bounds__(256, 8) void gather_kernel(
    const uint3* __restrict__ g12, const int* __restrict__ soff,
    const uint32_t* __restrict__ coef, const int* __restrict__ row_ptr,
    const uint32_t* __restrict__ Wrbfp, const float* __restrict__ brbf,
    float* __restrict__ dv, float* __restrict__ ds)
{
    const int ch   = threadIdx.x & 127;
    const int node = blockIdx.x * 2 + (threadIdx.x >> 7);

    uint32_t wq0[10], wq1[10], wq2[10];
    #pragma unroll
    for (int j = 0; j < 10; ++j) {
        wq0[j] = Wrbfp[(j * 3 + 0) * 128 + ch];
        wq1[j] = Wrbfp[(j * 3 + 1) * 128 + ch];
        wq2[j] = Wrbfp[(j * 3 + 2) * 128 + ch];
    }
    #pragma unroll
    for (int j = 0; j < 10; ++j) {
        asm volatile("" : "+v"(wq0[j]), "+v"(wq1[j]), "+v"(wq2[j]));
    }
    const float br0 = brbf[ch], br1 = brbf[128 + ch], br2 = brbf[256 + ch];

    const int beg = row_ptr[node];
    const int end = row_ptr[node + 1];
    const int nb  = (end - beg) >> 2;

    float a0 = 0.f, a1 = 0.f, a2 = 0.f, as = 0.f;

    uint3 A3[4], B3[4];

#define LOADB(P3, bi) do {                                                    \
    const int iu_ = __builtin_amdgcn_readfirstlane(beg + (bi) * 4);           \
    const int* sp_ = soff + iu_;                                              \
    P3[0] = g12[sp_[0] + ch];                                                 \
    P3[1] = g12[sp_[1] + ch];                                                 \
    P3[2] = g12[sp_[2] + ch];                                                 \
    P3[3] = g12[sp_[3] + ch];                                                 \
    const uint32_t* cq_ = coef + (size_t)iu_ * CSTRIDE;                       \
    const uint32_t t0_ = cq_[0],  t1_ = cq_[16],                              \
                   t2_ = cq_[32], t3_ = cq_[48];                              \
    asm volatile("" :: "s"(t0_), "s"(t1_), "s"(t2_), "s"(t3_));               \
} while (0)

#define CONSUME(P3, bi) do {                                                  \
    const uint32_t* cp_ = coef +                                              \
        (size_t)__builtin_amdgcn_readfirstlane(beg + (bi) * 4) * CSTRIDE;     \
    _Pragma("unroll")                                                         \
    for (int k = 0; k < 4; ++k) {                                             \
        const float ux = __uint_as_float(cp_[k * CSTRIDE + 0]);               \
        const float uy = __uint_as_float(cp_[k * CSTRIDE + 1]);               \
        const float uz = __uint_as_float(cp_[k * CSTRIDE + 2]);               \
        const float fc = __uint_as_float(cp_[k * CSTRIDE + 3]);               \
        float W0 = fc * br0;                                                  \
        float W1 = fc * br1;                                                  \
        float W2 = fc * br2;                                                  \
        _Pragma("unroll")                                                     \
        for (int j = 0; j < 10; ++j) {                                        \
            U32H2 cc; cc.u = cp_[k * CSTRIDE + 4 + j];                        \
            U32H2 w0_; w0_.u = wq0[j];                                        \
            U32H2 w1_; w1_.u = wq1[j];                                        \
            U32H2 w2_; w2_.u = wq2[j];                                        \
            W0 = __builtin_amdgcn_fdot2(cc.h, w0_.h, W0, false);              \
            W1 = __builtin_amdgcn_fdot2(cc.h, w1_.h, W1, false);              \
            W2 = __builtin_amdgcn_fdot2(cc.h, w2_.h, W2, false);              \
        }                                                                     \
        const uint32_t p0 = P3[k].x, p1 = P3[k].y, p2 = P3[k].z;              \
        const float xv = blo(p0) * W0;                                        \
        const float xs = bhi(p0) * W1;                                        \
        const float xd = blo(p1) * W2;                                        \
        a0 += bhi(p1) * xv + ux * xd;                                         \
        a1 += blo(p2) * xv + uy * xd;                                         \
        a2 += bhi(p2) * xv + uz * xd;                                         \
        as += xs;                                                             \
    }                                                                         \
} while (0)

    if (nb > 0) {
        const int last = nb - 1;
        LOADB(A3, 0);
        LOADB(B3, (1 < last ? 1 : last));
        int b = 0;
        for (; b + 2 < nb; b += 2) {
            CONSUME(A3, b);
            LOADB(A3, b + 2);
            CONSUME(B3, b + 1);
            LOADB(B3, (b + 3 < last ? b + 3 : last));
        }
        const int rem = nb - b;
        CONSUME(A3, b);
        if (rem == 2) CONSUME(B3, b + 1);
    }

    // tail (0..3 edges)
    for (int i = beg + (nb << 2); i < end; ++i) {
        const int iu = __builtin_amdgcn_readfirstlane(i);
        const uint3 P = g12[soff[iu] + ch];
        const uint32_t* cp = coef + (size_t)iu * CSTRIDE;
        const float ux = __uint_as_float(cp[0]);
        const float uy = __uint_as_float(cp[1]);
        const float uz = __uint_as_float(cp[2]);
        const float fc = __uint_as_float(cp[3]);
        float W0 = fc * br0;
        float W1 = fc * br1;
        float W2 = fc * br2;
        #pragma unroll
        for (int j = 0; j < 10; ++j) {
            U32H2 cc; cc.u = cp[4 + j];
            U32H2 w0_; w0_.u = wq0[j];
            U32H2 w1_; w1_.u = wq1[j];
            U32H2 w2_; w2_.u = wq2[j];
            W0 = __builtin_amdgcn_fdot2(cc.h, w0_.h, W0, false);
            W1 = __builtin_amdgcn_fdot2(cc.h, w1_.h, W1, false);
            W2 = __builtin_amdgcn_fdot2(cc.h, w2_.h, W2, false);
        }
        const uint32_t p0 = P.x, p1 = P.y, p2 = P.z;
        const float xv = blo(p0) * W0;
        const float xs = bhi(p0) * W1;
        const float xd = blo(p1) * W2;
        a0 += bhi(p1) * xv + ux * xd;
        a1 += blo(p2) * xv + uy * xd;
        a2 += bhi(p2) * xv + uz * xd;
        as += xs;
    }

#undef LOADB
#undef CONSUME

    const size_t orow = (size_t)node * 384;
    dv[orow + ch]       = a0;
    dv[orow + 128 + ch] = a1;
    dv[orow + 256 + ch] = a2;
    ds[(size_t)node * HID + ch] = as;
}

extern "C" void kernel_launch(void* const* d_in, const int* in_sizes, int n_in,
                              void* d_out, int out_size, void* d_ws, size_t ws_size,
                              hipStream_t stream)
{
    const float* s    = (const float*)d_in[0];
    const float* v    = (const float*)d_in[1];
    const float* r_ij = (const float*)d_in[2];
    const int*   esrc = (const int*)d_in[3];
    const int*   edst = (const int*)d_in[4];
    const float* W1   = (const float*)d_in[5];
    const float* b1   = (const float*)d_in[6];
    const float* W2   = (const float*)d_in[7];
    const float* b2   = (const float*)d_in[8];
    const float* Wrbf = (const float*)d_in[9];
    const float* brbf = (const float*)d_in[10];

    float* out = (float*)d_out;
    float* dv  = out;                                   // (16384,3,128)
    float* ds  = out + (size_t)N_NODES * 3 * HID;       // (16384,128)

    // workspace layout — pad after row_ptr so row_ptr[16384] cannot alias
    // cur[0] (the R4 crash).
    char* ws = (char*)d_ws;
    uint3*    g12     = (uint3*)   (ws + 0);            // 25,165,824 B
    uint32_t* coef    = (uint32_t*)(ws + 25165824);     // 16,777,216 B
    int*      soff    = (int*)     (ws + 41943040);     //  1,048,576 B
    int*      cnt     = (int*)     (ws + 42991616);     //     65,536 B
    int*      row_ptr = (int*)     (ws + 43057152);     //     65,540 B used
    int*      cur     = (int*)     (ws + 43122816);     //     65,536 B
    uint32_t* W1p     = (uint32_t*)(ws + 43188352);     //     32,768 B
    uint32_t* W2p     = (uint32_t*)(ws + 43221120);     //     98,304 B
    uint32_t* Wrbfp   = (uint32_t*)(ws + 43319424);     //     15,360 B

    prep_kernel<<<208, 256, 0, stream>>>(W1, W2, Wrbf, cnt, W1p, W2p, Wrbfp);
    phi_kernel<<<N_NODES / PB, 512, 0, stream>>>(s, v, W1p, b1, W2p, b2,
                                                 edst, cnt, g12);
    scan_kernel<<<1, 256, 0, stream>>>(cnt, row_ptr, cur);
    scatter_kernel<<<N_EDGES / 256, 256, 0, stream>>>(r_ij, esrc, edst, cur,
                                                      soff, coef);
    gather_kernel<<<N_NODES / 2, 256, 0, stream>>>(g12, soff, coef, row_ptr,
                                                   Wrbfp, brbf, dv, ds);
}

// Round 16
// 374.869 us; speedup vs baseline: 1.2538x; 1.2538x over previous
//
#include <hip/hip_runtime.h>
#include <math.h>
#include <stdint.h>

#define N_NODES 16384
#define N_EDGES 262144
#define HID 128
#define NRBF 20
#define CUTOFF 5.0f
#define PI_F 3.14159265358979323846f

#define CSTRIDE 16

typedef __attribute__((ext_vector_type(2))) __fp16 half2_t;
union U32H2 { uint32_t u; half2_t h; float f; };

__device__ inline unsigned short f2bf(float f) {
    unsigned int u = __float_as_uint(f);
    u = u + 0x7FFFu + ((u >> 16) & 1u);
    return (unsigned short)(u >> 16);
}
__device__ inline uint32_t pack2(float lo, float hi) {
    return (uint32_t)f2bf(lo) | ((uint32_t)f2bf(hi) << 16);
}
__device__ inline float blo(uint32_t u) { return __uint_as_float(u << 16); }
__device__ inline float bhi(uint32_t u) { return __uint_as_float(u & 0xFFFF0000u); }
__device__ inline uint32_t pkh2(float a, float b) {
    U32H2 u; u.h = __builtin_amdgcn_cvt_pkrtz(a, b); return u.u;
}

// ---------------------------------------------------------------------------
// Kernel 0: prep — zero cnt AND pre-pack W1/W2/Wrbf as f16 pairs (once).
// ---------------------------------------------------------------------------
__global__ __launch_bounds__(256) void prep_kernel(
    const float* __restrict__ W1, const float* __restrict__ W2,
    const float* __restrict__ Wrbf,
    int* __restrict__ cnt, uint32_t* __restrict__ W1p,
    uint32_t* __restrict__ W2p, uint32_t* __restrict__ Wrbfp)
{
    const int id = blockIdx.x * 256 + threadIdx.x;
    if (id < 16384) {
        cnt[id] = 0;
    } else if (id < 24576) {
        const int i = id - 16384;
        const int kp = i >> 7, t = i & 127;
        W1p[i] = pkh2(W1[(size_t)(2 * kp) * HID + t],
                      W1[(size_t)(2 * kp + 1) * HID + t]);
    } else if (id < 49152) {
        const int i = id - 24576;
        const int kp = i / 384, rem = i % 384;
        W2p[i] = pkh2(W2[(size_t)(2 * kp) * 384 + rem],
                      W2[(size_t)(2 * kp + 1) * 384 + rem]);
    } else if (id < 49152 + 3840) {
        const int i = id - 49152;
        const int j = i / 384, rem = i % 384;
        Wrbfp[i] = pkh2(Wrbf[(size_t)(2 * j) * 384 + rem],
                        Wrbf[(size_t)(2 * j + 1) * 384 + rem]);
    }
}

// ---------------------------------------------------------------------------
// Kernel 1: phi = silu(s@W1+b1)@W2+b2 via fdot2 on pre-packed weights.
// 512 threads/block, 32 nodes/block. Fused histogram. Writes 12 B/channel
// records g12[node*128+ch] = {(phi0,phi1),(phi2,v0),(v1,v2)} bf16 pairs.
// ---------------------------------------------------------------------------
#define PB 32
__global__ __launch_bounds__(512, 4) void phi_kernel(
    const float* __restrict__ s, const float* __restrict__ v,
    const uint32_t* __restrict__ W1p, const float* __restrict__ b1,
    const uint32_t* __restrict__ W2p, const float* __restrict__ b2,
    const int* __restrict__ edst, int* __restrict__ cnt,
    uint3* __restrict__ g12)
{
    const int tid = threadIdx.x;
    const int ch  = tid & 127;
    const int sub = tid >> 7;            // 0..3 -> nodes sub*8 .. sub*8+7
    const int node0 = blockIdx.x * PB;

    atomicAdd(&cnt[edst[blockIdx.x * 512 + tid]], 1);

    __shared__ uint32_t sL2[PB][64];     // 8 KB
    __shared__ float    hL[PB][HID];     // 16 KB
    __shared__ uint32_t hL2[PB][64];     // 8 KB

    #pragma unroll
    for (int q = 0; q < 4; ++q) {
        const int idx = q * 512 + tid;
        const int i = idx >> 6, c = idx & 63;
        const float2 sv = *(const float2*)&s[(size_t)(node0 + i) * HID + 2 * c];
        sL2[i][c] = pkh2(sv.x, sv.y);
    }
    __syncthreads();

    float h[8];
    const float bb1 = b1[ch];
    #pragma unroll
    for (int i = 0; i < 8; ++i) h[i] = bb1;

    for (int kp = 0; kp < 64; kp += 2) {
        U32H2 wa; wa.u = W1p[kp * 128 + ch];
        U32H2 wb; wb.u = W1p[(kp + 1) * 128 + ch];
        #pragma unroll
        for (int i = 0; i < 8; ++i) {
            U32H2 ca; ca.u = sL2[sub * 8 + i][kp];
            U32H2 cb; cb.u = sL2[sub * 8 + i][kp + 1];
            h[i] = __builtin_amdgcn_fdot2(ca.h, wa.h, h[i], false);
            h[i] = __builtin_amdgcn_fdot2(cb.h, wb.h, h[i], false);
        }
    }
    #pragma unroll
    for (int i = 0; i < 8; ++i) {
        const float x = h[i];
        hL[sub * 8 + i][ch] = x / (1.0f + expf(-x));
    }
    __syncthreads();
    #pragma unroll
    for (int q = 0; q < 4; ++q) {
        const int idx = q * 512 + tid;
        const int i = idx >> 6, c = idx & 63;
        hL2[i][c] = pkh2(hL[i][2 * c], hL[i][2 * c + 1]);
    }
    __syncthreads();

    float a0[8], a1[8], a2[8];
    #pragma unroll
    for (int i = 0; i < 8; ++i) { a0[i] = 0.f; a1[i] = 0.f; a2[i] = 0.f; }

    for (int kp = 0; kp < 64; ++kp) {
        U32H2 wA; wA.u = W2p[(kp * 3 + 0) * 128 + ch];
        U32H2 wB; wB.u = W2p[(kp * 3 + 1) * 128 + ch];
        U32H2 wC; wC.u = W2p[(kp * 3 + 2) * 128 + ch];
        #pragma unroll
        for (int i = 0; i < 8; ++i) {
            U32H2 hh; hh.u = hL2[sub * 8 + i][kp];
            a0[i] = __builtin_amdgcn_fdot2(hh.h, wA.h, a0[i], false);
            a1[i] = __builtin_amdgcn_fdot2(hh.h, wB.h, a1[i], false);
            a2[i] = __builtin_amdgcn_fdot2(hh.h, wC.h, a2[i], false);
        }
    }
    const float bb2a = b2[ch], bb2b = b2[128 + ch], bb2c = b2[256 + ch];
    #pragma unroll
    for (int i = 0; i < 8; ++i) {
        const int node = node0 + sub * 8 + i;
        const size_t nrow = (size_t)node * 384;
        const float p0 = a0[i] + bb2a;
        const float p1 = a1[i] + bb2b;
        const float p2 = a2[i] + bb2c;
        const float v0 = v[nrow + ch];
        const float v1 = v[nrow + 128 + ch];
        const float v2 = v[nrow + 256 + ch];
        g12[(size_t)node * HID + ch] =
            make_uint3(pack2(p0, p1), pack2(p2, v0), pack2(v1, v2));
    }
}

// ---------------------------------------------------------------------------
// CSR build: scan -> scatter
// ---------------------------------------------------------------------------
__global__ __launch_bounds__(256) void scan_kernel(const int* __restrict__ cnt,
                                                   int* __restrict__ row_ptr,
                                                   int* __restrict__ cur)
{
    __shared__ int part[256];
    const int tid = threadIdx.x;
    const int4* c4 = (const int4*)cnt;

    int4 loc[16];
    int s = 0;
    #pragma unroll
    for (int j = 0; j < 16; ++j) {
        loc[j] = c4[tid * 16 + j];
        s += loc[j].x + loc[j].y + loc[j].z + loc[j].w;
    }
    part[tid] = s;
    __syncthreads();
    #pragma unroll
    for (int d = 1; d < 256; d <<= 1) {
        const int add = (tid >= d) ? part[tid - d] : 0;
        __syncthreads();
        part[tid] += add;
        __syncthreads();
    }
    int off = (tid == 0) ? 0 : part[tid - 1];
    const int base = tid * 64;
    #pragma unroll
    for (int j = 0; j < 16; ++j) {
        const int4 q = loc[j];
        row_ptr[base + j*4 + 0] = off; cur[base + j*4 + 0] = off; off += q.x;
        row_ptr[base + j*4 + 1] = off; cur[base + j*4 + 1] = off; off += q.y;
        row_ptr[base + j*4 + 2] = off; cur[base + j*4 + 2] = off; off += q.z;
        row_ptr[base + j*4 + 3] = off; cur[base + j*4 + 3] = off; off += q.w;
    }
    if (tid == 255) row_ptr[16384] = off;
}

__global__ __launch_bounds__(256) void scatter_kernel(
    const float* __restrict__ r_ij, const int* __restrict__ esrc,
    const int* __restrict__ edst, int* __restrict__ cur,
    int* __restrict__ soff, uint32_t* __restrict__ coef)
{
    const int e = blockIdx.x * 256 + threadIdx.x;
    if (e >= N_EDGES) return;
    const float rx = r_ij[(size_t)e * 3 + 0];
    const float ry = r_ij[(size_t)e * 3 + 1];
    const float rz = r_ij[(size_t)e * 3 + 2];
    const float d = sqrtf(rx * rx + ry * ry + rz * rz);
    const float inv_d = 1.0f / d;
    float sx, cx;
    sincosf((PI_F / CUTOFF) * d, &sx, &cx);
    const float fcut = (d < CUTOFF) ? 0.5f * (cx + 1.0f) : 0.0f;

    float cf[NRBF];
    const float gfac = inv_d * fcut;
    const float twocx = 2.0f * cx;
    float sm1 = sx, sm2 = 0.0f;
    cf[0] = sx * gfac;
    #pragma unroll
    for (int n = 1; n < NRBF; ++n) {
        const float sn = twocx * sm1 - sm2;
        sm2 = sm1; sm1 = sn;
        cf[n] = sn * gfac;
    }

    uint32_t cp[10];
    #pragma unroll
    for (int j = 0; j < 10; ++j) cp[j] = pkh2(cf[2 * j], cf[2 * j + 1]);

    const int pos = atomicAdd(&cur[edst[e]], 1);
    soff[pos] = esrc[e] * 128;
    uint4* c4 = (uint4*)(coef + (size_t)pos * CSTRIDE);
    c4[0] = make_uint4(__float_as_uint(rx * inv_d), __float_as_uint(ry * inv_d),
                       __float_as_uint(rz * inv_d), __float_as_uint(fcut));
    c4[1] = make_uint4(cp[0], cp[1], cp[2], cp[3]);
    c4[2] = make_uint4(cp[4], cp[5], cp[6], cp[7]);
    c4[3] = make_uint4(cp[8], cp[9], 0u, 0u);
}

// ---------------------------------------------------------------------------
// Gather: node per 128-thread group; batch-4 edges; depth-2 ping-pong;
// ONE dwordx3 (12 B) gather per edge-thread; scalar coef/soff loads + K$
// warm; fdot2 on pre-packed weights pinned via asm.
// launch_bounds(256,6): the PROVEN register regime (R14: VGPR 40, no
// spill). (256,8) spilled catastrophically (R15) — do not raise.
// ---------------------------------------------------------------------------
__global__ __launch_bounds__(256, 6) void gather_kernel(
    const uint3* __restrict__ g12, const int* __restrict__ soff,
    const uint32_t* __restrict__ coef, const int* __restrict__ row_ptr,
    const uint32_t* __restrict__ Wrbfp, const float* __restrict__ brbf,
    float* __restrict__ dv, float* __restrict__ ds)
{
    const int ch   = threadIdx.x & 127;
    const int node = blockIdx.x * 2 + (threadIdx.x >> 7);

    uint32_t wq0[10], wq1[10], wq2[10];
    #pragma unroll
    for (int j = 0; j < 10; ++j) {
        wq0[j] = Wrbfp[(j * 3 + 0) * 128 + ch];
        wq1[j] = Wrbfp[(j * 3 + 1) * 128 + ch];
        wq2[j] = Wrbfp[(j * 3 + 2) * 128 + ch];
    }
    #pragma unroll
    for (int j = 0; j < 10; ++j) {
        asm volatile("" : "+v"(wq0[j]), "+v"(wq1[j]), "+v"(wq2[j]));
    }
    const float br0 = brbf[ch], br1 = brbf[128 + ch], br2 = brbf[256 + ch];

    const int beg = row_ptr[node];
    const int end = row_ptr[node + 1];
    const int nb  = (end - beg) >> 2;

    float a0 = 0.f, a1 = 0.f, a2 = 0.f, as = 0.f;

    uint3 A3[4], B3[4];

#define LOADB(P3, bi) do {                                                    \
    const int iu_ = __builtin_amdgcn_readfirstlane(beg + (bi) * 4);           \
    const int* sp_ = soff + iu_;                                              \
    P3[0] = g12[sp_[0] + ch];                                                 \
    P3[1] = g12[sp_[1] + ch];                                                 \
    P3[2] = g12[sp_[2] + ch];                                                 \
    P3[3] = g12[sp_[3] + ch];                                                 \
    const uint32_t* cq_ = coef + (size_t)iu_ * CSTRIDE;                       \
    const uint32_t t0_ = cq_[0],  t1_ = cq_[16],                              \
                   t2_ = cq_[32], t3_ = cq_[48];                              \
    asm volatile("" :: "s"(t0_), "s"(t1_), "s"(t2_), "s"(t3_));               \
} while (0)

#define CONSUME(P3, bi) do {                                                  \
    const uint32_t* cp_ = coef +                                              \
        (size_t)__builtin_amdgcn_readfirstlane(beg + (bi) * 4) * CSTRIDE;     \
    _Pragma("unroll")                                                         \
    for (int k = 0; k < 4; ++k) {                                             \
        const float ux = __uint_as_float(cp_[k * CSTRIDE + 0]);               \
        const float uy = __uint_as_float(cp_[k * CSTRIDE + 1]);               \
        const float uz = __uint_as_float(cp_[k * CSTRIDE + 2]);               \
        const float fc = __uint_as_float(cp_[k * CSTRIDE + 3]);               \
        float W0 = fc * br0;                                                  \
        float W1 = fc * br1;                                                  \
        float W2 = fc * br2;                                                  \
        _Pragma("unroll")                                                     \
        for (int j = 0; j < 10; ++j) {                                        \
            U32H2 cc; cc.u = cp_[k * CSTRIDE + 4 + j];                        \
            U32H2 w0_; w0_.u = wq0[j];                                        \
            U32H2 w1_; w1_.u = wq1[j];                                        \
            U32H2 w2_; w2_.u = wq2[j];                                        \
            W0 = __builtin_amdgcn_fdot2(cc.h, w0_.h, W0, false);              \
            W1 = __builtin_amdgcn_fdot2(cc.h, w1_.h, W1, false);              \
            W2 = __builtin_amdgcn_fdot2(cc.h, w2_.h, W2, false);              \
        }                                                                     \
        const uint32_t p0 = P3[k].x, p1 = P3[k].y, p2 = P3[k].z;              \
        const float xv = blo(p0) * W0;                                        \
        const float xs = bhi(p0) * W1;                                        \
        const float xd = blo(p1) * W2;                                        \
        a0 += bhi(p1) * xv + ux * xd;                                         \
        a1 += blo(p2) * xv + uy * xd;                                         \
        a2 += bhi(p2) * xv + uz * xd;                                         \
        as += xs;                                                             \
    }                                                                         \
} while (0)

    if (nb > 0) {
        const int last = nb - 1;
        LOADB(A3, 0);
        LOADB(B3, (1 < last ? 1 : last));
        int b = 0;
        for (; b + 2 < nb; b += 2) {
            CONSUME(A3, b);
            LOADB(A3, b + 2);
            CONSUME(B3, b + 1);
            LOADB(B3, (b + 3 < last ? b + 3 : last));
        }
        const int rem = nb - b;
        CONSUME(A3, b);
        if (rem == 2) CONSUME(B3, b + 1);
    }

    // tail (0..3 edges)
    for (int i = beg + (nb << 2); i < end; ++i) {
        const int iu = __builtin_amdgcn_readfirstlane(i);
        const uint3 P = g12[soff[iu] + ch];
        const uint32_t* cp = coef + (size_t)iu * CSTRIDE;
        const float ux = __uint_as_float(cp[0]);
        const float uy = __uint_as_float(cp[1]);
        const float uz = __uint_as_float(cp[2]);
        const float fc = __uint_as_float(cp[3]);
        float W0 = fc * br0;
        float W1 = fc * br1;
        float W2 = fc * br2;
        #pragma unroll
        for (int j = 0; j < 10; ++j) {
            U32H2 cc; cc.u = cp[4 + j];
            U32H2 w0_; w0_.u = wq0[j];
            U32H2 w1_; w1_.u = wq1[j];
            U32H2 w2_; w2_.u = wq2[j];
            W0 = __builtin_amdgcn_fdot2(cc.h, w0_.h, W0, false);
            W1 = __builtin_amdgcn_fdot2(cc.h, w1_.h, W1, false);
            W2 = __builtin_amdgcn_fdot2(cc.h, w2_.h, W2, false);
        }
        const uint32_t p0 = P.x, p1 = P.y, p2 = P.z;
        const float xv = blo(p0) * W0;
        const float xs = bhi(p0) * W1;
        const float xd = blo(p1) * W2;
        a0 += bhi(p1) * xv + ux * xd;
        a1 += blo(p2) * xv + uy * xd;
        a2 += bhi(p2) * xv + uz * xd;
        as += xs;
    }

#undef LOADB
#undef CONSUME

    const size_t orow = (size_t)node * 384;
    dv[orow + ch]       = a0;
    dv[orow + 128 + ch] = a1;
    dv[orow + 256 + ch] = a2;
    ds[(size_t)node * HID + ch] = as;
}

extern "C" void kernel_launch(void* const* d_in, const int* in_sizes, int n_in,
                              void* d_out, int out_size, void* d_ws, size_t ws_size,
                              hipStream_t stream)
{
    const float* s    = (const float*)d_in[0];
    const float* v    = (const float*)d_in[1];
    const float* r_ij = (const float*)d_in[2];
    const int*   esrc = (const int*)d_in[3];
    const int*   edst = (const int*)d_in[4];
    const float* W1   = (const float*)d_in[5];
    const float* b1   = (const float*)d_in[6];
    const float* W2   = (const float*)d_in[7];
    const float* b2   = (const float*)d_in[8];
    const float* Wrbf = (const float*)d_in[9];
    const float* brbf = (const float*)d_in[10];

    float* out = (float*)d_out;
    float* dv  = out;                                   // (16384,3,128)
    float* ds  = out + (size_t)N_NODES * 3 * HID;       // (16384,128)

    // workspace layout — pad after row_ptr so row_ptr[16384] cannot alias
    // cur[0] (the R4 crash).
    char* ws = (char*)d_ws;
    uint3*    g12     = (uint3*)   (ws + 0);            // 25,165,824 B
    uint32_t* coef    = (uint32_t*)(ws + 25165824);     // 16,777,216 B
    int*      soff    = (int*)     (ws + 41943040);     //  1,048,576 B
    int*      cnt     = (int*)     (ws + 42991616);     //     65,536 B
    int*      row_ptr = (int*)     (ws + 43057152);     //     65,540 B used
    int*      cur     = (int*)     (ws + 43122816);     //     65,536 B
    uint32_t* W1p     = (uint32_t*)(ws + 43188352);     //     32,768 B
    uint32_t* W2p     = (uint32_t*)(ws + 43221120);     //     98,304 B
    uint32_t* Wrbfp   = (uint32_t*)(ws + 43319424);     //     15,360 B

    prep_kernel<<<208, 256, 0, stream>>>(W1, W2, Wrbf, cnt, W1p, W2p, Wrbfp);
    phi_kernel<<<N_NODES / PB, 512, 0, stream>>>(s, v, W1p, b1, W2p, b2,
                                                 edst, cnt, g12);
    scan_kernel<<<1, 256, 0, stream>>>(cnt, row_ptr, cur);
    scatter_kernel<<<N_EDGES / 256, 256, 0, stream>>>(r_ij, esrc, edst, cur,
                                                      soff, coef);
    gather_kernel<<<N_NODES / 2, 256, 0, stream>>>(g12, soff, coef, row_ptr,
                                                   Wrbfp, brbf, dv, ds);
}

// Round 17
// 140.998 us; speedup vs baseline: 3.3336x; 2.6587x over previous
//
#include <hip/hip_runtime.h>
#include <math.h>
#include <stdint.h>

#define N_NODES 16384
#define N_EDGES 262144
#define HID 128
#define NRBF 20
#define CUTOFF 5.0f
#define PI_F 3.14159265358979323846f

#define CSTRIDE 16

typedef __attribute__((ext_vector_type(2))) __fp16 half2_t;
union U32H2 { uint32_t u; half2_t h; float f; };

__device__ inline unsigned short f2bf(float f) {
    unsigned int u = __float_as_uint(f);
    u = u + 0x7FFFu + ((u >> 16) & 1u);
    return (unsigned short)(u >> 16);
}
__device__ inline uint32_t pack2(float lo, float hi) {
    return (uint32_t)f2bf(lo) | ((uint32_t)f2bf(hi) << 16);
}
__device__ inline float blo(uint32_t u) { return __uint_as_float(u << 16); }
__device__ inline float bhi(uint32_t u) { return __uint_as_float(u & 0xFFFF0000u); }
__device__ inline uint32_t pkh2(float a, float b) {
    U32H2 u; u.h = __builtin_amdgcn_cvt_pkrtz(a, b); return u.u;
}

// ---------------------------------------------------------------------------
// Kernel 0: prep — zero cnt AND pre-pack W1/W2/Wrbf as f16 pairs (once).
// ---------------------------------------------------------------------------
__global__ __launch_bounds__(256) void prep_kernel(
    const float* __restrict__ W1, const float* __restrict__ W2,
    const float* __restrict__ Wrbf,
    int* __restrict__ cnt, uint32_t* __restrict__ W1p,
    uint32_t* __restrict__ W2p, uint32_t* __restrict__ Wrbfp)
{
    const int id = blockIdx.x * 256 + threadIdx.x;
    if (id < 16384) {
        cnt[id] = 0;
    } else if (id < 24576) {
        const int i = id - 16384;
        const int kp = i >> 7, t = i & 127;
        W1p[i] = pkh2(W1[(size_t)(2 * kp) * HID + t],
                      W1[(size_t)(2 * kp + 1) * HID + t]);
    } else if (id < 49152) {
        const int i = id - 24576;
        const int kp = i / 384, rem = i % 384;
        W2p[i] = pkh2(W2[(size_t)(2 * kp) * 384 + rem],
                      W2[(size_t)(2 * kp + 1) * 384 + rem]);
    } else if (id < 49152 + 3840) {
        const int i = id - 49152;
        const int j = i / 384, rem = i % 384;
        Wrbfp[i] = pkh2(Wrbf[(size_t)(2 * j) * 384 + rem],
                        Wrbf[(size_t)(2 * j + 1) * 384 + rem]);
    }
}

// ---------------------------------------------------------------------------
// Kernel 1: phi = silu(s@W1+b1)@W2+b2 via fdot2 on pre-packed weights.
// 512 threads/block, 32 nodes/block. Fused histogram. Outputs guv (uint2)
// + gw (uint32), bf16 pairs: {(phi0,phi1),(phi2,v0)} and (v1,v2).
// ---------------------------------------------------------------------------
#define PB 32
__global__ __launch_bounds__(512, 4) void phi_kernel(
    const float* __restrict__ s, const float* __restrict__ v,
    const uint32_t* __restrict__ W1p, const float* __restrict__ b1,
    const uint32_t* __restrict__ W2p, const float* __restrict__ b2,
    const int* __restrict__ edst, int* __restrict__ cnt,
    uint2* __restrict__ guv, uint32_t* __restrict__ gw)
{
    const int tid = threadIdx.x;
    const int ch  = tid & 127;
    const int sub = tid >> 7;            // 0..3 -> nodes sub*8 .. sub*8+7
    const int node0 = blockIdx.x * PB;

    atomicAdd(&cnt[edst[blockIdx.x * 512 + tid]], 1);

    __shared__ uint32_t sL2[PB][64];     // 8 KB
    __shared__ float    hL[PB][HID];     // 16 KB
    __shared__ uint32_t hL2[PB][64];     // 8 KB

    #pragma unroll
    for (int q = 0; q < 4; ++q) {
        const int idx = q * 512 + tid;
        const int i = idx >> 6, c = idx & 63;
        const float2 sv = *(const float2*)&s[(size_t)(node0 + i) * HID + 2 * c];
        sL2[i][c] = pkh2(sv.x, sv.y);
    }
    __syncthreads();

    float h[8];
    const float bb1 = b1[ch];
    #pragma unroll
    for (int i = 0; i < 8; ++i) h[i] = bb1;

    for (int kp = 0; kp < 64; kp += 2) {
        U32H2 wa; wa.u = W1p[kp * 128 + ch];
        U32H2 wb; wb.u = W1p[(kp + 1) * 128 + ch];
        #pragma unroll
        for (int i = 0; i < 8; ++i) {
            U32H2 ca; ca.u = sL2[sub * 8 + i][kp];
            U32H2 cb; cb.u = sL2[sub * 8 + i][kp + 1];
            h[i] = __builtin_amdgcn_fdot2(ca.h, wa.h, h[i], false);
            h[i] = __builtin_amdgcn_fdot2(cb.h, wb.h, h[i], false);
        }
    }
    #pragma unroll
    for (int i = 0; i < 8; ++i) {
        const float x = h[i];
        hL[sub * 8 + i][ch] = x / (1.0f + expf(-x));
    }
    __syncthreads();
    #pragma unroll
    for (int q = 0; q < 4; ++q) {
        const int idx = q * 512 + tid;
        const int i = idx >> 6, c = idx & 63;
        hL2[i][c] = pkh2(hL[i][2 * c], hL[i][2 * c + 1]);
    }
    __syncthreads();

    float a0[8], a1[8], a2[8];
    #pragma unroll
    for (int i = 0; i < 8; ++i) { a0[i] = 0.f; a1[i] = 0.f; a2[i] = 0.f; }

    for (int kp = 0; kp < 64; ++kp) {
        U32H2 wA; wA.u = W2p[(kp * 3 + 0) * 128 + ch];
        U32H2 wB; wB.u = W2p[(kp * 3 + 1) * 128 + ch];
        U32H2 wC; wC.u = W2p[(kp * 3 + 2) * 128 + ch];
        #pragma unroll
        for (int i = 0; i < 8; ++i) {
            U32H2 hh; hh.u = hL2[sub * 8 + i][kp];
            a0[i] = __builtin_amdgcn_fdot2(hh.h, wA.h, a0[i], false);
            a1[i] = __builtin_amdgcn_fdot2(hh.h, wB.h, a1[i], false);
            a2[i] = __builtin_amdgcn_fdot2(hh.h, wC.h, a2[i], false);
        }
    }
    const float bb2a = b2[ch], bb2b = b2[128 + ch], bb2c = b2[256 + ch];
    #pragma unroll
    for (int i = 0; i < 8; ++i) {
        const int node = node0 + sub * 8 + i;
        const size_t nrow = (size_t)node * 384;
        const float p0 = a0[i] + bb2a;
        const float p1 = a1[i] + bb2b;
        const float p2 = a2[i] + bb2c;
        const float v0 = v[nrow + ch];
        const float v1 = v[nrow + 128 + ch];
        const float v2 = v[nrow + 256 + ch];
        const size_t gi = (size_t)node * HID + ch;
        guv[gi] = make_uint2(pack2(p0, p1), pack2(p2, v0));
        gw[gi]  = pack2(v1, v2);
    }
}

// ---------------------------------------------------------------------------
// CSR build: scan -> scatter
// ---------------------------------------------------------------------------
__global__ __launch_bounds__(256) void scan_kernel(const int* __restrict__ cnt,
                                                   int* __restrict__ row_ptr,
                                                   int* __restrict__ cur)
{
    __shared__ int part[256];
    const int tid = threadIdx.x;
    const int4* c4 = (const int4*)cnt;

    int4 loc[16];
    int s = 0;
    #pragma unroll
    for (int j = 0; j < 16; ++j) {
        loc[j] = c4[tid * 16 + j];
        s += loc[j].x + loc[j].y + loc[j].z + loc[j].w;
    }
    part[tid] = s;
    __syncthreads();
    #pragma unroll
    for (int d = 1; d < 256; d <<= 1) {
        const int add = (tid >= d) ? part[tid - d] : 0;
        __syncthreads();
        part[tid] += add;
        __syncthreads();
    }
    int off = (tid == 0) ? 0 : part[tid - 1];
    const int base = tid * 64;
    #pragma unroll
    for (int j = 0; j < 16; ++j) {
        const int4 q = loc[j];
        row_ptr[base + j*4 + 0] = off; cur[base + j*4 + 0] = off; off += q.x;
        row_ptr[base + j*4 + 1] = off; cur[base + j*4 + 1] = off; off += q.y;
        row_ptr[base + j*4 + 2] = off; cur[base + j*4 + 2] = off; off += q.z;
        row_ptr[base + j*4 + 3] = off; cur[base + j*4 + 3] = off; off += q.w;
    }
    if (tid == 255) row_ptr[16384] = off;
}

__global__ __launch_bounds__(256) void scatter_kernel(
    const float* __restrict__ r_ij, const int* __restrict__ esrc,
    const int* __restrict__ edst, int* __restrict__ cur,
    int* __restrict__ soff, uint32_t* __restrict__ coef)
{
    const int e = blockIdx.x * 256 + threadIdx.x;
    if (e >= N_EDGES) return;
    const float rx = r_ij[(size_t)e * 3 + 0];
    const float ry = r_ij[(size_t)e * 3 + 1];
    const float rz = r_ij[(size_t)e * 3 + 2];
    const float d = sqrtf(rx * rx + ry * ry + rz * rz);
    const float inv_d = 1.0f / d;
    float sx, cx;
    sincosf((PI_F / CUTOFF) * d, &sx, &cx);
    const float fcut = (d < CUTOFF) ? 0.5f * (cx + 1.0f) : 0.0f;

    float cf[NRBF];
    const float gfac = inv_d * fcut;
    const float twocx = 2.0f * cx;
    float sm1 = sx, sm2 = 0.0f;
    cf[0] = sx * gfac;
    #pragma unroll
    for (int n = 1; n < NRBF; ++n) {
        const float sn = twocx * sm1 - sm2;
        sm2 = sm1; sm1 = sn;
        cf[n] = sn * gfac;
    }

    uint32_t cp[10];
    #pragma unroll
    for (int j = 0; j < 10; ++j) cp[j] = pkh2(cf[2 * j], cf[2 * j + 1]);

    const int pos = atomicAdd(&cur[edst[e]], 1);
    soff[pos] = esrc[e] * 128;
    uint4* c4 = (uint4*)(coef + (size_t)pos * CSTRIDE);
    c4[0] = make_uint4(__float_as_uint(rx * inv_d), __float_as_uint(ry * inv_d),
                       __float_as_uint(rz * inv_d), __float_as_uint(fcut));
    c4[1] = make_uint4(cp[0], cp[1], cp[2], cp[3]);
    c4[2] = make_uint4(cp[4], cp[5], cp[6], cp[7]);
    c4[3] = make_uint4(cp[8], cp[9], 0u, 0u);
}

// ---------------------------------------------------------------------------
// Gather: EXACT R14 configuration (72 us, no spills): node per 128-thread
// group; batch-4 edges; depth-2 ping-pong; uint2+u32 12 B gathers; scalar
// coef/soff loads + K$ warm; fdot2 on pre-packed weights pinned via asm.
// launch_bounds(256,6). DO NOT: raise waves/EU (R15 spill), deepen prefetch
// (R13 spill), or merge loads into uint3 (R16 scratch pathology).
// ---------------------------------------------------------------------------
__global__ __launch_bounds__(256, 6) void gather_kernel(
    const uint2* __restrict__ guv, const uint32_t* __restrict__ gw,
    const int* __restrict__ soff, const uint32_t* __restrict__ coef,
    const int* __restrict__ row_ptr, const uint32_t* __restrict__ Wrbfp,
    const float* __restrict__ brbf,
    float* __restrict__ dv, float* __restrict__ ds)
{
    const int ch   = threadIdx.x & 127;
    const int node = blockIdx.x * 2 + (threadIdx.x >> 7);

    uint32_t wq0[10], wq1[10], wq2[10];
    #pragma unroll
    for (int j = 0; j < 10; ++j) {
        wq0[j] = Wrbfp[(j * 3 + 0) * 128 + ch];
        wq1[j] = Wrbfp[(j * 3 + 1) * 128 + ch];
        wq2[j] = Wrbfp[(j * 3 + 2) * 128 + ch];
    }
    #pragma unroll
    for (int j = 0; j < 10; ++j) {
        asm volatile("" : "+v"(wq0[j]), "+v"(wq1[j]), "+v"(wq2[j]));
    }
    const float br0 = brbf[ch], br1 = brbf[128 + ch], br2 = brbf[256 + ch];

    const int beg = row_ptr[node];
    const int end = row_ptr[node + 1];
    const int nb  = (end - beg) >> 2;

    float a0 = 0.f, a1 = 0.f, a2 = 0.f, as = 0.f;

    uint2 A2[4], B2[4];
    uint32_t Aw[4], Bw[4];

#define LOADB(P2, Pw, bi) do {                                                \
    const int iu_ = __builtin_amdgcn_readfirstlane(beg + (bi) * 4);           \
    const int* sp_ = soff + iu_;                                              \
    const int o0 = sp_[0] + ch, o1 = sp_[1] + ch,                             \
              o2 = sp_[2] + ch, o3 = sp_[3] + ch;                             \
    P2[0] = guv[o0]; P2[1] = guv[o1]; P2[2] = guv[o2]; P2[3] = guv[o3];       \
    Pw[0] = gw[o0];  Pw[1] = gw[o1];  Pw[2] = gw[o2];  Pw[3] = gw[o3];        \
    const uint32_t* cq_ = coef + (size_t)iu_ * CSTRIDE;                       \
    const uint32_t t0_ = cq_[0],  t1_ = cq_[16],                              \
                   t2_ = cq_[32], t3_ = cq_[48];                              \
    asm volatile("" :: "s"(t0_), "s"(t1_), "s"(t2_), "s"(t3_));               \
} while (0)

#define CONSUME(P2, Pw, bi) do {                                              \
    const uint32_t* cp_ = coef +                                              \
        (size_t)__builtin_amdgcn_readfirstlane(beg + (bi) * 4) * CSTRIDE;     \
    _Pragma("unroll")                                                         \
    for (int k = 0; k < 4; ++k) {                                             \
        const float ux = __uint_as_float(cp_[k * CSTRIDE + 0]);               \
        const float uy = __uint_as_float(cp_[k * CSTRIDE + 1]);               \
        const float uz = __uint_as_float(cp_[k * CSTRIDE + 2]);               \
        const float fc = __uint_as_float(cp_[k * CSTRIDE + 3]);               \
        float W0 = fc * br0;                                                  \
        float W1 = fc * br1;                                                  \
        float W2 = fc * br2;                                                  \
        _Pragma("unroll")                                                     \
        for (int j = 0; j < 10; ++j) {                                        \
            U32H2 cc; cc.u = cp_[k * CSTRIDE + 4 + j];                        \
            U32H2 w0_; w0_.u = wq0[j];                                        \
            U32H2 w1_; w1_.u = wq1[j];                                        \
            U32H2 w2_; w2_.u = wq2[j];                                        \
            W0 = __builtin_amdgcn_fdot2(cc.h, w0_.h, W0, false);              \
            W1 = __builtin_amdgcn_fdot2(cc.h, w1_.h, W1, false);              \
            W2 = __builtin_amdgcn_fdot2(cc.h, w2_.h, W2, false);              \
        }                                                                     \
        const uint32_t p0 = P2[k].x, p1 = P2[k].y, p2 = Pw[k];                \
        const float xv = blo(p0) * W0;                                        \
        const float xs = bhi(p0) * W1;                                        \
        const float xd = blo(p1) * W2;                                        \
        a0 += bhi(p1) * xv + ux * xd;                                         \
        a1 += blo(p2) * xv + uy * xd;                                         \
        a2 += bhi(p2) * xv + uz * xd;                                         \
        as += xs;                                                             \
    }                                                                         \
} while (0)

    if (nb > 0) {
        const int last = nb - 1;
        LOADB(A2, Aw, 0);
        LOADB(B2, Bw, (1 < last ? 1 : last));
        int b = 0;
        for (; b + 2 < nb; b += 2) {
            CONSUME(A2, Aw, b);
            LOADB(A2, Aw, b + 2);
            CONSUME(B2, Bw, b + 1);
            LOADB(B2, Bw, (b + 3 < last ? b + 3 : last));
        }
        const int rem = nb - b;
        CONSUME(A2, Aw, b);
        if (rem == 2) CONSUME(B2, Bw, b + 1);
    }

    // tail (0..3 edges)
    for (int i = beg + (nb << 2); i < end; ++i) {
        const int iu = __builtin_amdgcn_readfirstlane(i);
        const int o = soff[iu] + ch;
        const uint2 P = guv[o];
        const uint32_t p2 = gw[o];
        const uint32_t* cp = coef + (size_t)iu * CSTRIDE;
        const float ux = __uint_as_float(cp[0]);
        const float uy = __uint_as_float(cp[1]);
        const float uz = __uint_as_float(cp[2]);
        const float fc = __uint_as_float(cp[3]);
        float W0 = fc * br0;
        float W1 = fc * br1;
        float W2 = fc * br2;
        #pragma unroll
        for (int j = 0; j < 10; ++j) {
            U32H2 cc; cc.u = cp[4 + j];
            U32H2 w0_; w0_.u = wq0[j];
            U32H2 w1_; w1_.u = wq1[j];
            U32H2 w2_; w2_.u = wq2[j];
            W0 = __builtin_amdgcn_fdot2(cc.h, w0_.h, W0, false);
            W1 = __builtin_amdgcn_fdot2(cc.h, w1_.h, W1, false);
            W2 = __builtin_amdgcn_fdot2(cc.h, w2_.h, W2, false);
        }
        const uint32_t p0 = P.x, p1 = P.y;
        const float xv = blo(p0) * W0;
        const float xs = bhi(p0) * W1;
        const float xd = blo(p1) * W2;
        a0 += bhi(p1) * xv + ux * xd;
        a1 += blo(p2) * xv + uy * xd;
        a2 += bhi(p2) * xv + uz * xd;
        as += xs;
    }

#undef LOADB
#undef CONSUME

    const size_t orow = (size_t)node * 384;
    dv[orow + ch]       = a0;
    dv[orow + 128 + ch] = a1;
    dv[orow + 256 + ch] = a2;
    ds[(size_t)node * HID + ch] = as;
}

extern "C" void kernel_launch(void* const* d_in, const int* in_sizes, int n_in,
                              void* d_out, int out_size, void* d_ws, size_t ws_size,
                              hipStream_t stream)
{
    const float* s    = (const float*)d_in[0];
    const float* v    = (const float*)d_in[1];
    const float* r_ij = (const float*)d_in[2];
    const int*   esrc = (const int*)d_in[3];
    const int*   edst = (const int*)d_in[4];
    const float* W1   = (const float*)d_in[5];
    const float* b1   = (const float*)d_in[6];
    const float* W2   = (const float*)d_in[7];
    const float* b2   = (const float*)d_in[8];
    const float* Wrbf = (const float*)d_in[9];
    const float* brbf = (const float*)d_in[10];

    float* out = (float*)d_out;
    float* dv  = out;                                   // (16384,3,128)
    float* ds  = out + (size_t)N_NODES * 3 * HID;       // (16384,128)

    // workspace layout — pad after row_ptr so row_ptr[16384] cannot alias
    // cur[0] (the R4 crash).
    char* ws = (char*)d_ws;
    uint2*    guv     = (uint2*)   (ws + 0);            // 16,777,216 B
    uint32_t* gw      = (uint32_t*)(ws + 16777216);     //  8,388,608 B
    uint32_t* coef    = (uint32_t*)(ws + 25165824);     // 16,777,216 B
    int*      soff    = (int*)     (ws + 41943040);     //  1,048,576 B
    int*      cnt     = (int*)     (ws + 42991616);     //     65,536 B
    int*      row_ptr = (int*)     (ws + 43057152);     //     65,540 B used
    int*      cur     = (int*)     (ws + 43122816);     //     65,536 B
    uint32_t* W1p     = (uint32_t*)(ws + 43188352);     //     32,768 B
    uint32_t* W2p     = (uint32_t*)(ws + 43221120);     //     98,304 B
    uint32_t* Wrbfp   = (uint32_t*)(ws + 43319424);     //     15,360 B

    prep_kernel<<<208, 256, 0, stream>>>(W1, W2, Wrbf, cnt, W1p, W2p, Wrbfp);
    phi_kernel<<<N_NODES / PB, 512, 0, stream>>>(s, v, W1p, b1, W2p, b2,
                                                 edst, cnt, guv, gw);
    scan_kernel<<<1, 256, 0, stream>>>(cnt, row_ptr, cur);
    scatter_kernel<<<N_EDGES / 256, 256, 0, stream>>>(r_ij, esrc, edst, cur,
                                                      soff, coef);
    gather_kernel<<<N_NODES / 2, 256, 0, stream>>>(guv, gw, soff, coef, row_ptr,
                                                   Wrbfp, brbf, dv, ds);
}

// Round 18
// 136.624 us; speedup vs baseline: 3.4403x; 1.0320x over previous
//
#include <hip/hip_runtime.h>
#include <math.h>
#include <stdint.h>

#define N_NODES 16384
#define N_EDGES 262144
#define HID 128
#define NRBF 20
#define CUTOFF 5.0f
#define PI_F 3.14159265358979323846f

#define CSTRIDE 16

typedef __attribute__((ext_vector_type(2))) __fp16 half2_t;
union U32H2 { uint32_t u; half2_t h; float f; };

__device__ inline unsigned short f2bf(float f) {
    unsigned int u = __float_as_uint(f);
    u = u + 0x7FFFu + ((u >> 16) & 1u);
    return (unsigned short)(u >> 16);
}
__device__ inline uint32_t pack2(float lo, float hi) {
    return (uint32_t)f2bf(lo) | ((uint32_t)f2bf(hi) << 16);
}
__device__ inline float blo(uint32_t u) { return __uint_as_float(u << 16); }
__device__ inline float bhi(uint32_t u) { return __uint_as_float(u & 0xFFFF0000u); }
__device__ inline uint32_t pkh2(float a, float b) {
    U32H2 u; u.h = __builtin_amdgcn_cvt_pkrtz(a, b); return u.u;
}

// ---------------------------------------------------------------------------
// Kernel 0: prep — pack W1/W2/Wrbf as f16 pairs AND edge histogram.
// cnt must be zeroed (memsetAsync) before this kernel.
// ids: [0,8192) W1p | [8192,32768) W2p | [32768,36608) Wrbfp |
//      [36608,298752) histogram over N_EDGES
// ---------------------------------------------------------------------------
__global__ __launch_bounds__(256) void prep_kernel(
    const float* __restrict__ W1, const float* __restrict__ W2,
    const float* __restrict__ Wrbf, const int* __restrict__ edst,
    int* __restrict__ cnt, uint32_t* __restrict__ W1p,
    uint32_t* __restrict__ W2p, uint32_t* __restrict__ Wrbfp)
{
    const int id = blockIdx.x * 256 + threadIdx.x;
    if (id < 8192) {
        const int kp = id >> 7, t = id & 127;
        W1p[id] = pkh2(W1[(size_t)(2 * kp) * HID + t],
                       W1[(size_t)(2 * kp + 1) * HID + t]);
    } else if (id < 32768) {
        const int i = id - 8192;
        const int kp = i / 384, rem = i % 384;
        W2p[i] = pkh2(W2[(size_t)(2 * kp) * 384 + rem],
                      W2[(size_t)(2 * kp + 1) * 384 + rem]);
    } else if (id < 36608) {
        const int i = id - 32768;
        const int j = i / 384, rem = i % 384;
        Wrbfp[i] = pkh2(Wrbf[(size_t)(2 * j) * 384 + rem],
                        Wrbf[(size_t)(2 * j + 1) * 384 + rem]);
    } else if (id < 36608 + N_EDGES) {
        atomicAdd(&cnt[edst[id - 36608]], 1);
    }
}

// ---------------------------------------------------------------------------
// CSR scan
// ---------------------------------------------------------------------------
__global__ __launch_bounds__(256) void scan_kernel(const int* __restrict__ cnt,
                                                   int* __restrict__ row_ptr,
                                                   int* __restrict__ cur)
{
    __shared__ int part[256];
    const int tid = threadIdx.x;
    const int4* c4 = (const int4*)cnt;

    int4 loc[16];
    int s = 0;
    #pragma unroll
    for (int j = 0; j < 16; ++j) {
        loc[j] = c4[tid * 16 + j];
        s += loc[j].x + loc[j].y + loc[j].z + loc[j].w;
    }
    part[tid] = s;
    __syncthreads();
    #pragma unroll
    for (int d = 1; d < 256; d <<= 1) {
        const int add = (tid >= d) ? part[tid - d] : 0;
        __syncthreads();
        part[tid] += add;
        __syncthreads();
    }
    int off = (tid == 0) ? 0 : part[tid - 1];
    const int base = tid * 64;
    #pragma unroll
    for (int j = 0; j < 16; ++j) {
        const int4 q = loc[j];
        row_ptr[base + j*4 + 0] = off; cur[base + j*4 + 0] = off; off += q.x;
        row_ptr[base + j*4 + 1] = off; cur[base + j*4 + 1] = off; off += q.y;
        row_ptr[base + j*4 + 2] = off; cur[base + j*4 + 2] = off; off += q.z;
        row_ptr[base + j*4 + 3] = off; cur[base + j*4 + 3] = off; off += q.w;
    }
    if (tid == 255) row_ptr[16384] = off;
}

// ---------------------------------------------------------------------------
// Kernel 2 (FUSED): scatter (512 edges/block) then phi (32 nodes/block).
// Scatter's latency/store work drains under phi's fdot2 compute.
// 512 blocks x 512 threads.
// ---------------------------------------------------------------------------
#define PB 32
__global__ __launch_bounds__(512, 4) void phi_scatter_kernel(
    const float* __restrict__ s, const float* __restrict__ v,
    const uint32_t* __restrict__ W1p, const float* __restrict__ b1,
    const uint32_t* __restrict__ W2p, const float* __restrict__ b2,
    const float* __restrict__ r_ij, const int* __restrict__ esrc,
    const int* __restrict__ edst, int* __restrict__ cur,
    int* __restrict__ soff, uint32_t* __restrict__ coef,
    uint2* __restrict__ guv, uint32_t* __restrict__ gw)
{
    const int tid = threadIdx.x;
    const int ch  = tid & 127;
    const int sub = tid >> 7;            // 0..3 -> nodes sub*8 .. sub*8+7
    const int node0 = blockIdx.x * PB;

    // ---- scatter phase: one edge per thread --------------------------------
    {
        const int e = blockIdx.x * 512 + tid;
        const float rx = r_ij[(size_t)e * 3 + 0];
        const float ry = r_ij[(size_t)e * 3 + 1];
        const float rz = r_ij[(size_t)e * 3 + 2];
        const float d = sqrtf(rx * rx + ry * ry + rz * rz);
        const float inv_d = 1.0f / d;
        float sx, cx;
        sincosf((PI_F / CUTOFF) * d, &sx, &cx);
        const float fcut = (d < CUTOFF) ? 0.5f * (cx + 1.0f) : 0.0f;

        float cf[NRBF];
        const float gfac = inv_d * fcut;
        const float twocx = 2.0f * cx;
        float sm1 = sx, sm2 = 0.0f;
        cf[0] = sx * gfac;
        #pragma unroll
        for (int n = 1; n < NRBF; ++n) {
            const float sn = twocx * sm1 - sm2;
            sm2 = sm1; sm1 = sn;
            cf[n] = sn * gfac;
        }

        uint32_t cp[10];
        #pragma unroll
        for (int j = 0; j < 10; ++j) cp[j] = pkh2(cf[2 * j], cf[2 * j + 1]);

        const int pos = atomicAdd(&cur[edst[e]], 1);
        soff[pos] = esrc[e] * 128;
        uint4* c4 = (uint4*)(coef + (size_t)pos * CSTRIDE);
        c4[0] = make_uint4(__float_as_uint(rx * inv_d),
                           __float_as_uint(ry * inv_d),
                           __float_as_uint(rz * inv_d),
                           __float_as_uint(fcut));
        c4[1] = make_uint4(cp[0], cp[1], cp[2], cp[3]);
        c4[2] = make_uint4(cp[4], cp[5], cp[6], cp[7]);
        c4[3] = make_uint4(cp[8], cp[9], 0u, 0u);
    }

    // ---- phi phase ---------------------------------------------------------
    __shared__ uint32_t sL2[PB][64];     // 8 KB
    __shared__ float    hL[PB][HID];     // 16 KB
    __shared__ uint32_t hL2[PB][64];     // 8 KB

    #pragma unroll
    for (int q = 0; q < 4; ++q) {
        const int idx = q * 512 + tid;
        const int i = idx >> 6, c = idx & 63;
        const float2 sv = *(const float2*)&s[(size_t)(node0 + i) * HID + 2 * c];
        sL2[i][c] = pkh2(sv.x, sv.y);
    }
    __syncthreads();

    float h[8];
    const float bb1 = b1[ch];
    #pragma unroll
    for (int i = 0; i < 8; ++i) h[i] = bb1;

    for (int kp = 0; kp < 64; kp += 2) {
        U32H2 wa; wa.u = W1p[kp * 128 + ch];
        U32H2 wb; wb.u = W1p[(kp + 1) * 128 + ch];
        #pragma unroll
        for (int i = 0; i < 8; ++i) {
            U32H2 ca; ca.u = sL2[sub * 8 + i][kp];
            U32H2 cb; cb.u = sL2[sub * 8 + i][kp + 1];
            h[i] = __builtin_amdgcn_fdot2(ca.h, wa.h, h[i], false);
            h[i] = __builtin_amdgcn_fdot2(cb.h, wb.h, h[i], false);
        }
    }
    #pragma unroll
    for (int i = 0; i < 8; ++i) {
        const float x = h[i];
        hL[sub * 8 + i][ch] = x / (1.0f + expf(-x));
    }
    __syncthreads();
    #pragma unroll
    for (int q = 0; q < 4; ++q) {
        const int idx = q * 512 + tid;
        const int i = idx >> 6, c = idx & 63;
        hL2[i][c] = pkh2(hL[i][2 * c], hL[i][2 * c + 1]);
    }
    __syncthreads();

    float a0[8], a1[8], a2[8];
    #pragma unroll
    for (int i = 0; i < 8; ++i) { a0[i] = 0.f; a1[i] = 0.f; a2[i] = 0.f; }

    for (int kp = 0; kp < 64; ++kp) {
        U32H2 wA; wA.u = W2p[(kp * 3 + 0) * 128 + ch];
        U32H2 wB; wB.u = W2p[(kp * 3 + 1) * 128 + ch];
        U32H2 wC; wC.u = W2p[(kp * 3 + 2) * 128 + ch];
        #pragma unroll
        for (int i = 0; i < 8; ++i) {
            U32H2 hh; hh.u = hL2[sub * 8 + i][kp];
            a0[i] = __builtin_amdgcn_fdot2(hh.h, wA.h, a0[i], false);
            a1[i] = __builtin_amdgcn_fdot2(hh.h, wB.h, a1[i], false);
            a2[i] = __builtin_amdgcn_fdot2(hh.h, wC.h, a2[i], false);
        }
    }
    const float bb2a = b2[ch], bb2b = b2[128 + ch], bb2c = b2[256 + ch];
    #pragma unroll
    for (int i = 0; i < 8; ++i) {
        const int node = node0 + sub * 8 + i;
        const size_t nrow = (size_t)node * 384;
        const float p0 = a0[i] + bb2a;
        const float p1 = a1[i] + bb2b;
        const float p2 = a2[i] + bb2c;
        const float v0 = v[nrow + ch];
        const float v1 = v[nrow + 128 + ch];
        const float v2 = v[nrow + 256 + ch];
        const size_t gi = (size_t)node * HID + ch;
        guv[gi] = make_uint2(pack2(p0, p1), pack2(p2, v0));
        gw[gi]  = pack2(v1, v2);
    }
}

// ---------------------------------------------------------------------------
// Gather: EXACT R14 configuration (72 us, no spills): node per 128-thread
// group; batch-4 edges; depth-2 ping-pong; uint2+u32 12 B gathers; scalar
// coef/soff loads + K$ warm; fdot2 on pre-packed weights pinned via asm.
// launch_bounds(256,6). DO NOT: raise waves/EU (R15 spill), deepen prefetch
// (R13 spill), or merge loads into uint3 (R16 scratch pathology).
// ---------------------------------------------------------------------------
__global__ __launch_bounds__(256, 6) void gather_kernel(
    const uint2* __restrict__ guv, const uint32_t* __restrict__ gw,
    const int* __restrict__ soff, const uint32_t* __restrict__ coef,
    const int* __restrict__ row_ptr, const uint32_t* __restrict__ Wrbfp,
    const float* __restrict__ brbf,
    float* __restrict__ dv, float* __restrict__ ds)
{
    const int ch   = threadIdx.x & 127;
    const int node = blockIdx.x * 2 + (threadIdx.x >> 7);

    uint32_t wq0[10], wq1[10], wq2[10];
    #pragma unroll
    for (int j = 0; j < 10; ++j) {
        wq0[j] = Wrbfp[(j * 3 + 0) * 128 + ch];
        wq1[j] = Wrbfp[(j * 3 + 1) * 128 + ch];
        wq2[j] = Wrbfp[(j * 3 + 2) * 128 + ch];
    }
    #pragma unroll
    for (int j = 0; j < 10; ++j) {
        asm volatile("" : "+v"(wq0[j]), "+v"(wq1[j]), "+v"(wq2[j]));
    }
    const float br0 = brbf[ch], br1 = brbf[128 + ch], br2 = brbf[256 + ch];

    const int beg = row_ptr[node];
    const int end = row_ptr[node + 1];
    const int nb  = (end - beg) >> 2;

    float a0 = 0.f, a1 = 0.f, a2 = 0.f, as = 0.f;

    uint2 A2[4], B2[4];
    uint32_t Aw[4], Bw[4];

#define LOADB(P2, Pw, bi) do {                                                \
    const int iu_ = __builtin_amdgcn_readfirstlane(beg + (bi) * 4);           \
    const int* sp_ = soff + iu_;                                              \
    const int o0 = sp_[0] + ch, o1 = sp_[1] + ch,                             \
              o2 = sp_[2] + ch, o3 = sp_[3] + ch;                             \
    P2[0] = guv[o0]; P2[1] = guv[o1]; P2[2] = guv[o2]; P2[3] = guv[o3];       \
    Pw[0] = gw[o0];  Pw[1] = gw[o1];  Pw[2] = gw[o2];  Pw[3] = gw[o3];        \
    const uint32_t* cq_ = coef + (size_t)iu_ * CSTRIDE;                       \
    const uint32_t t0_ = cq_[0],  t1_ = cq_[16],                              \
                   t2_ = cq_[32], t3_ = cq_[48];                              \
    asm volatile("" :: "s"(t0_), "s"(t1_), "s"(t2_), "s"(t3_));               \
} while (0)

#define CONSUME(P2, Pw, bi) do {                                              \
    const uint32_t* cp_ = coef +                                              \
        (size_t)__builtin_amdgcn_readfirstlane(beg + (bi) * 4) * CSTRIDE;     \
    _Pragma("unroll")                                                         \
    for (int k = 0; k < 4; ++k) {                                             \
        const float ux = __uint_as_float(cp_[k * CSTRIDE + 0]);               \
        const float uy = __uint_as_float(cp_[k * CSTRIDE + 1]);               \
        const float uz = __uint_as_float(cp_[k * CSTRIDE + 2]);               \
        const float fc = __uint_as_float(cp_[k * CSTRIDE + 3]);               \
        float W0 = fc * br0;                                                  \
        float W1 = fc * br1;                                                  \
        float W2 = fc * br2;                                                  \
        _Pragma("unroll")                                                     \
        for (int j = 0; j < 10; ++j) {                                        \
            U32H2 cc; cc.u = cp_[k * CSTRIDE + 4 + j];                        \
            U32H2 w0_; w0_.u = wq0[j];                                        \
            U32H2 w1_; w1_.u = wq1[j];                                        \
            U32H2 w2_; w2_.u = wq2[j];                                        \
            W0 = __builtin_amdgcn_fdot2(cc.h, w0_.h, W0, false);              \
            W1 = __builtin_amdgcn_fdot2(cc.h, w1_.h, W1, false);              \
            W2 = __builtin_amdgcn_fdot2(cc.h, w2_.h, W2, false);              \
        }                                                                     \
        const uint32_t p0 = P2[k].x, p1 = P2[k].y, p2 = Pw[k];                \
        const float xv = blo(p0) * W0;                                        \
        const float xs = bhi(p0) * W1;                                        \
        const float xd = blo(p1) * W2;                                        \
        a0 += bhi(p1) * xv + ux * xd;                                         \
        a1 += blo(p2) * xv + uy * xd;                                         \
        a2 += bhi(p2) * xv + uz * xd;                                         \
        as += xs;                                                             \
    }                                                                         \
} while (0)

    if (nb > 0) {
        const int last = nb - 1;
        LOADB(A2, Aw, 0);
        LOADB(B2, Bw, (1 < last ? 1 : last));
        int b = 0;
        for (; b + 2 < nb; b += 2) {
            CONSUME(A2, Aw, b);
            LOADB(A2, Aw, b + 2);
            CONSUME(B2, Bw, b + 1);
            LOADB(B2, Bw, (b + 3 < last ? b + 3 : last));
        }
        const int rem = nb - b;
        CONSUME(A2, Aw, b);
        if (rem == 2) CONSUME(B2, Bw, b + 1);
    }

    // tail (0..3 edges)
    for (int i = beg + (nb << 2); i < end; ++i) {
        const int iu = __builtin_amdgcn_readfirstlane(i);
        const int o = soff[iu] + ch;
        const uint2 P = guv[o];
        const uint32_t p2 = gw[o];
        const uint32_t* cp = coef + (size_t)iu * CSTRIDE;
        const float ux = __uint_as_float(cp[0]);
        const float uy = __uint_as_float(cp[1]);
        const float uz = __uint_as_float(cp[2]);
        const float fc = __uint_as_float(cp[3]);
        float W0 = fc * br0;
        float W1 = fc * br1;
        float W2 = fc * br2;
        #pragma unroll
        for (int j = 0; j < 10; ++j) {
            U32H2 cc; cc.u = cp[4 + j];
            U32H2 w0_; w0_.u = wq0[j];
            U32H2 w1_; w1_.u = wq1[j];
            U32H2 w2_; w2_.u = wq2[j];
            W0 = __builtin_amdgcn_fdot2(cc.h, w0_.h, W0, false);
            W1 = __builtin_amdgcn_fdot2(cc.h, w1_.h, W1, false);
            W2 = __builtin_amdgcn_fdot2(cc.h, w2_.h, W2, false);
        }
        const uint32_t p0 = P.x, p1 = P.y;
        const float xv = blo(p0) * W0;
        const float xs = bhi(p0) * W1;
        const float xd = blo(p1) * W2;
        a0 += bhi(p1) * xv + ux * xd;
        a1 += blo(p2) * xv + uy * xd;
        a2 += bhi(p2) * xv + uz * xd;
        as += xs;
    }

#undef LOADB
#undef CONSUME

    const size_t orow = (size_t)node * 384;
    dv[orow + ch]       = a0;
    dv[orow + 128 + ch] = a1;
    dv[orow + 256 + ch] = a2;
    ds[(size_t)node * HID + ch] = as;
}

extern "C" void kernel_launch(void* const* d_in, const int* in_sizes, int n_in,
                              void* d_out, int out_size, void* d_ws, size_t ws_size,
                              hipStream_t stream)
{
    const float* s    = (const float*)d_in[0];
    const float* v    = (const float*)d_in[1];
    const float* r_ij = (const float*)d_in[2];
    const int*   esrc = (const int*)d_in[3];
    const int*   edst = (const int*)d_in[4];
    const float* W1   = (const float*)d_in[5];
    const float* b1   = (const float*)d_in[6];
    const float* W2   = (const float*)d_in[7];
    const float* b2   = (const float*)d_in[8];
    const float* Wrbf = (const float*)d_in[9];
    const float* brbf = (const float*)d_in[10];

    float* out = (float*)d_out;
    float* dv  = out;                                   // (16384,3,128)
    float* ds  = out + (size_t)N_NODES * 3 * HID;       // (16384,128)

    // workspace layout — pad after row_ptr so row_ptr[16384] cannot alias
    // cur[0] (the R4 crash).
    char* ws = (char*)d_ws;
    uint2*    guv     = (uint2*)   (ws + 0);            // 16,777,216 B
    uint32_t* gw      = (uint32_t*)(ws + 16777216);     //  8,388,608 B
    uint32_t* coef    = (uint32_t*)(ws + 25165824);     // 16,777,216 B
    int*      soff    = (int*)     (ws + 41943040);     //  1,048,576 B
    int*      cnt     = (int*)     (ws + 42991616);     //     65,536 B
    int*      row_ptr = (int*)     (ws + 43057152);     //     65,540 B used
    int*      cur     = (int*)     (ws + 43122816);     //     65,536 B
    uint32_t* W1p     = (uint32_t*)(ws + 43188352);     //     32,768 B
    uint32_t* W2p     = (uint32_t*)(ws + 43221120);     //     98,304 B
    uint32_t* Wrbfp   = (uint32_t*)(ws + 43319424);     //     15,360 B

    hipMemsetAsync(cnt, 0, 16384 * sizeof(int), stream);

    prep_kernel<<<1167, 256, 0, stream>>>(W1, W2, Wrbf, edst, cnt,
                                          W1p, W2p, Wrbfp);
    scan_kernel<<<1, 256, 0, stream>>>(cnt, row_ptr, cur);
    phi_scatter_kernel<<<512, 512, 0, stream>>>(s, v, W1p, b1, W2p, b2,
                                                r_ij, esrc, edst, cur,
                                                soff, coef, guv, gw);
    gather_kernel<<<N_NODES / 2, 256, 0, stream>>>(guv, gw, soff, coef, row_ptr,
                                                   Wrbfp, brbf, dv, ds);
}